// Round 10
// baseline (280.251 us; speedup 1.0000x reference)
//
#include <hip/hip_runtime.h>
#include <math.h>

// Problem constants (from setup_inputs: B=2, L=512, D=256, H=64, S=4)
#define BB 2
#define LL 512
#define DD 256
#define HH 64
#define NSTEP 4
#define NTOK (BB * LL)   // 1024

__device__ __forceinline__ float geluf(float x) {
    return 0.5f * x * (1.0f + erff(x * 0.70710678118654752f));
}
__device__ __forceinline__ float sigmoidf_(float x) {
    return 1.0f / (1.0f + expf(-x));
}
// Fast exact-flavor gelu: A&S 7.1.26 erf approx, |err(erf)| <= 1.5e-7.
__device__ __forceinline__ float gelu_fast(float x) {
    float u = 0.70710678118654752f * x;
    float a = fabsf(u);
    float t = __builtin_amdgcn_rcpf(fmaf(0.3275911f, a, 1.0f));
    float p = fmaf(t, 1.061405429f, -1.453152027f);
    p = fmaf(t, p, 1.421413741f);
    p = fmaf(t, p, -0.284496736f);
    p = fmaf(t, p, 0.254829592f);
    p = p * t;
    float e = __expf(-u * u);
    float erfa = fmaf(-p, e, 1.0f);          // erf(|u|)
    float erfu = copysignf(erfa, u);
    return 0.5f * x * (1.0f + erfu);
}
#define F4C(v, j) ((j) == 0 ? (v).x : (j) == 1 ? (v).y : (j) == 2 ? (v).z : (v).w)

// ---------------------------------------------------------------------------
// Kernel 0: build frames from coords.
// ---------------------------------------------------------------------------
__global__ void build_frames_kernel(const float* __restrict__ coords,
                                    float* __restrict__ Rg, float* __restrict__ tg) {
    int idx = blockIdx.x * blockDim.x + threadIdx.x;
    if (idx >= NTOK) return;
    const float* c = coords + idx * 9;
    float Px = c[0], Py = c[1], Pz = c[2];
    float Cx = c[3], Cy = c[4], Cz = c[5];
    float Nx = c[6], Ny = c[7], Nz = c[8];
    float e1x = Nx - Cx, e1y = Ny - Cy, e1z = Nz - Cz;
    float n1 = fmaxf(sqrtf(e1x * e1x + e1y * e1y + e1z * e1z), 1e-12f);
    e1x /= n1; e1y /= n1; e1z /= n1;
    float ux = Px - Cx, uy = Py - Cy, uz = Pz - Cz;
    float du = ux * e1x + uy * e1y + uz * e1z;
    float e2x = ux - du * e1x, e2y = uy - du * e1y, e2z = uz - du * e1z;
    float n2 = fmaxf(sqrtf(e2x * e2x + e2y * e2y + e2z * e2z), 1e-12f);
    e2x /= n2; e2y /= n2; e2z /= n2;
    float e3x = e1y * e2z - e1z * e2y;
    float e3y = e1z * e2x - e1x * e2z;
    float e3z = e1x * e2y - e1y * e2x;
    float* Rp = Rg + idx * 9;
    Rp[0] = e1x; Rp[1] = e2x; Rp[2] = e3x;
    Rp[3] = e1y; Rp[4] = e2y; Rp[5] = e3y;
    Rp[6] = e1z; Rp[7] = e2z; Rp[8] = e3z;
    tg[idx * 3 + 0] = Cx; tg[idx * 3 + 1] = Cy; tg[idx * 3 + 2] = Cz;
}

// ---------------------------------------------------------------------------
// Kernel A (once): all 4 steps' LayerNorm of h -> hln[s][i][k]
// ---------------------------------------------------------------------------
__global__ __launch_bounds__(256) void ln4_kernel(
        const float* __restrict__ hIn,
        const float* __restrict__ lng, const float* __restrict__ lnb,
        float* __restrict__ hln) {
    __shared__ float redsh[8];
    const int i = blockIdx.x;
    const int tid = threadIdx.x;
    const int wv = tid >> 6, lane = tid & 63;
    float hv = hIn[(size_t)i * DD + tid];
    float s1 = hv, s2 = hv * hv;
#pragma unroll
    for (int off = 32; off > 0; off >>= 1) {
        s1 += __shfl_xor(s1, off);
        s2 += __shfl_xor(s2, off);
    }
    if (lane == 0) { redsh[wv * 2] = s1; redsh[wv * 2 + 1] = s2; }
    __syncthreads();
    float S1 = redsh[0] + redsh[2] + redsh[4] + redsh[6];
    float S2 = redsh[1] + redsh[3] + redsh[5] + redsh[7];
    float mu = S1 * (1.0f / DD);
    float var = S2 * (1.0f / DD) - mu * mu;
    float rs = rsqrtf(var + 1e-5f);
    float hn = (hv - mu) * rs;
#pragma unroll
    for (int s = 0; s < NSTEP; s++)
        hln[((size_t)s * NTOK + i) * DD + tid] = hn * lng[s * DD + tid] + lnb[s * DD + tid];
}

// ---------------------------------------------------------------------------
// Kernel A2 (once): fold w1/b1 per step into w1f[s][h][8].
// ---------------------------------------------------------------------------
__global__ void fold_w1_kernel(const float* __restrict__ w1all,
                               const float* __restrict__ b1all,
                               float* __restrict__ w1f) {
    const int s = blockIdx.x;
    const int h = threadIdx.x;   // 64
    const float* w1 = w1all + s * 7 * HH;
    float w5 = w1[5 * HH + h];
    float* o = w1f + ((size_t)s * HH + h) * 8;
    o[0] = w1[0 * HH + h];
    o[1] = w1[1 * HH + h];
    o[2] = w1[2 * HH + h];
    o[3] = w1[3 * HH + h];
    o[4] = fmaf(0.5f, w5, w1[4 * HH + h]);
    o[5] = w1[6 * HH + h];
    o[6] = fmaf(-0.5f, w5, b1all[s * HH + h]);
    o[7] = 0.0f;
}

// ---------------------------------------------------------------------------
// Kernel B (once): Wfus[s][64][512] = (w2[s] @ Wbot)/512, biasGA.
// ---------------------------------------------------------------------------
__global__ __launch_bounds__(256) void fuse_w_kernel(
        const float* __restrict__ w2all, const float* __restrict__ b2all,
        const float* __restrict__ gww, const float* __restrict__ gaw,
        const float* __restrict__ gwb, const float* __restrict__ gab,
        float* __restrict__ Wfus, float* __restrict__ biasGA) {
    __shared__ float bsh[256 * 17];   // 17 KB, padded stride 17

    const int bid = blockIdx.x;
    const int s = bid >> 5;
    const int gate = (bid >> 4) & 1;
    const int ct = bid & 15;
    const int c0 = ct * 16;
    const int tid = threadIdx.x;

    const float* Wb = (gate ? gaw : gww) + (size_t)s * 2 * DD * DD + (size_t)DD * DD;
    {
        const float* src = Wb + (size_t)tid * DD + c0;
        float4 a0 = *(const float4*)(src + 0);
        float4 a1 = *(const float4*)(src + 4);
        float4 a2 = *(const float4*)(src + 8);
        float4 a3 = *(const float4*)(src + 12);
        float* dst = &bsh[tid * 17];
        dst[0] = a0.x; dst[1] = a0.y; dst[2] = a0.z; dst[3] = a0.w;
        dst[4] = a1.x; dst[5] = a1.y; dst[6] = a1.z; dst[7] = a1.w;
        dst[8] = a2.x; dst[9] = a2.y; dst[10] = a2.z; dst[11] = a2.w;
        dst[12] = a3.x; dst[13] = a3.y; dst[14] = a3.z; dst[15] = a3.w;
    }
    __syncthreads();

    const int r = tid & 63;
    const int cg = tid >> 6;
    const float* w2p = w2all + (size_t)s * HH * DD + (size_t)r * DD;
    float4 acc = {0.f, 0.f, 0.f, 0.f};
#pragma unroll 4
    for (int k4 = 0; k4 < 64; k4++) {
        float4 wv = *(const float4*)(w2p + k4 * 4);
#pragma unroll
        for (int j = 0; j < 4; j++) {
            const float* bp = &bsh[(k4 * 4 + j) * 17 + cg * 4];
            float w = F4C(wv, j);
            acc.x = fmaf(w, bp[0], acc.x);
            acc.y = fmaf(w, bp[1], acc.y);
            acc.z = fmaf(w, bp[2], acc.z);
            acc.w = fmaf(w, bp[3], acc.w);
        }
    }
    acc.x *= (1.0f / 512.0f); acc.y *= (1.0f / 512.0f);
    acc.z *= (1.0f / 512.0f); acc.w *= (1.0f / 512.0f);
    *(float4*)&Wfus[((size_t)s * HH + r) * 512 + gate * 256 + c0 + cg * 4] = acc;

    if (tid < 16) {
        const float* b2 = b2all + s * DD;
        float a = 0.0f;
#pragma unroll 4
        for (int m = 0; m < 256; m++) a = fmaf(b2[m], bsh[m * 17 + tid], a);
        const float* gb = (gate ? gab : gwb) + s * DD;
        biasGA[(size_t)s * 512 + gate * 256 + c0 + tid] = a + gb[c0 + tid];
    }
}

// ---------------------------------------------------------------------------
// Kernel C (once): gpreH[s][i][gate*256+col] = hln[s][i] @ Wtop + biasGA.
// ---------------------------------------------------------------------------
__global__ __launch_bounds__(256) void gpreh_kernel(
        const float* __restrict__ hln,
        const float* __restrict__ gww, const float* __restrict__ gaw,
        const float* __restrict__ biasGA,
        float* __restrict__ gpreH) {
    __shared__ float hsh[16 * DD];   // 16 KB
    const int bid = blockIdx.x;
    const int s = bid >> 7;
    const int gate = (bid >> 6) & 1;
    const int mt = bid & 63;
    const int tid = threadIdx.x;     // = col

    const float* hsrc = hln + ((size_t)s * NTOK + mt * 16) * DD;
    for (int k = tid; k < 16 * DD; k += 256) hsh[k] = hsrc[k];
    __syncthreads();

    const float* W = (gate ? gaw : gww) + (size_t)s * 2 * DD * DD;  // top half
    float bias = biasGA[(size_t)s * 512 + gate * 256 + tid];
    float acc[16];
#pragma unroll
    for (int t = 0; t < 16; t++) acc[t] = bias;
#pragma unroll 4
    for (int k = 0; k < DD; k++) {
        float w = W[(size_t)k * DD + tid];
#pragma unroll
        for (int t = 0; t < 16; t++) acc[t] = fmaf(hsh[t * DD + k], w, acc[t]);
    }
    float* out = gpreH + ((size_t)s * NTOK + mt * 16) * 512 + gate * 256 + tid;
#pragma unroll
    for (int t = 0; t < 16; t++) out[(size_t)t * 512] = acc[t];
}

// ---------------------------------------------------------------------------
// Kernel D1 (per step): PAIR ONLY. Features -> SoA LDS; c-outer/k-inner gelu
// accumulation; asum written straight to global. No epilogue, no extra
// barriers. Grid 1024 x 256 thr, 4 blocks/CU.
// ---------------------------------------------------------------------------
__global__ __launch_bounds__(256, 4) void pair_kernel(
        const float* __restrict__ Rin, const float* __restrict__ tin,
        const float* __restrict__ w1fS,
        float* __restrict__ asumG) {
    __shared__ float Rsh[LL * 9];     // 18 KB
    __shared__ float tsh[LL * 3];     // 6 KB
    __shared__ float feats[6][LL];    // 12 KB SoA

    const int i = blockIdx.x;
    const int b = i >> 9;
    const int l = i & (LL - 1);
    const int tid = threadIdx.x;
    const int g = tid >> 6;
    const int hh = tid & 63;

    const float* Rb = Rin + (size_t)b * LL * 9;
    const float* tb = tin + (size_t)b * LL * 3;
    for (int k = tid; k < LL * 9; k += 256) Rsh[k] = Rb[k];
    for (int k = tid; k < LL * 3; k += 256) tsh[k] = tb[k];
    __syncthreads();

    float Ri[9];
#pragma unroll
    for (int k = 0; k < 9; k++) Ri[k] = Rsh[l * 9 + k];
    const float tix = tsh[l * 3 + 0], tiy = tsh[l * 3 + 1], tiz = tsh[l * 3 + 2];

    // Phase A: features for j = tid, tid+256 into SoA LDS
#pragma unroll
    for (int half = 0; half < 2; half++) {
        const int j = half * 256 + tid;
        float dx = tsh[j * 3 + 0] - tix;
        float dy = tsh[j * 3 + 1] - tiy;
        float dz = tsh[j * 3 + 2] - tiz;
        float dl0 = Ri[0] * dx + Ri[3] * dy + Ri[6] * dz;
        float dl1 = Ri[1] * dx + Ri[4] * dy + Ri[7] * dz;
        float dl2 = Ri[2] * dx + Ri[5] * dy + Ri[8] * dz;
        float dist = fmaxf(sqrtf(dx * dx + dy * dy + dz * dz), 1e-4f);
        float tr = 0.0f;
#pragma unroll
        for (int k = 0; k < 9; k++) tr = fmaf(Ri[k], Rsh[j * 9 + k], tr);
        feats[0][j] = dist;
        feats[1][j] = dl0;
        feats[2][j] = dl1;
        feats[3][j] = dl2;
        feats[4][j] = tr;
        feats[5][j] = __logf(dist);
    }
    __syncthreads();

    // Phase B: wave g covers h = g*16 + hp*8 + k; SGPR weights
    const int h0g = __builtin_amdgcn_readfirstlane(g) * 16;
#pragma unroll
    for (int hp = 0; hp < 2; hp++) {
        const float* wrow = w1fS + (size_t)(h0g + hp * 8) * 8;   // SGPR base
        float acc0 = 0.f, acc1 = 0.f, acc2 = 0.f, acc3 = 0.f;
        float acc4 = 0.f, acc5 = 0.f, acc6 = 0.f, acc7 = 0.f;
        for (int c = 0; c < 8; c++) {
            const int j = c * 64 + hh;
            const float F0 = feats[0][j];
            const float F1 = feats[1][j];
            const float F2 = feats[2][j];
            const float F3 = feats[3][j];
            const float F4 = feats[4][j];
            const float F5 = feats[5][j];
#pragma unroll
            for (int k = 0; k < 8; k++) {
                const float* wr = wrow + k * 8;
                float x = wr[6];
                x = fmaf(F0, wr[0], x);
                x = fmaf(F1, wr[1], x);
                x = fmaf(F2, wr[2], x);
                x = fmaf(F3, wr[3], x);
                x = fmaf(F4, wr[4], x);
                x = fmaf(F5, wr[5], x);
                float gv = gelu_fast(x);
                if (k == 0) acc0 += gv;
                else if (k == 1) acc1 += gv;
                else if (k == 2) acc2 += gv;
                else if (k == 3) acc3 += gv;
                else if (k == 4) acc4 += gv;
                else if (k == 5) acc5 += gv;
                else if (k == 6) acc6 += gv;
                else acc7 += gv;
            }
        }
        float accs[8] = {acc0, acc1, acc2, acc3, acc4, acc5, acc6, acc7};
#pragma unroll
        for (int k = 0; k < 8; k++) {
            float v = accs[k];
#pragma unroll
            for (int off = 1; off < 64; off <<= 1) v += __shfl_xor(v, off);
            if (hh == k) asumG[(size_t)i * HH + h0g + hp * 8 + k] = v;
        }
    }
}

// ---------------------------------------------------------------------------
// Kernel D2 (per step): EPILOGUE for 8 tokens/block, 512 threads, grid 128.
// gates via Wfus (K=64, amortized 8x), h_aug, LN2, fh MLP, frame update.
// ---------------------------------------------------------------------------
__global__ __launch_bounds__(512) void epi_kernel(
        const float* __restrict__ Rin, const float* __restrict__ tin,
        float* __restrict__ Rout, float* __restrict__ tout,
        const float* __restrict__ asumG,
        const float* __restrict__ WfusS, const float* __restrict__ gpreHS,
        const float* __restrict__ hIn,
        const float* __restrict__ fhlng, const float* __restrict__ fhlnb,
        const float* __restrict__ fhw1, const float* __restrict__ fhb1,
        const float* __restrict__ fhw2, const float* __restrict__ fhb2,
        float* __restrict__ outFinal, float* __restrict__ outStack, int s) {
    __shared__ float ash[8][HH];      // 2 KB
    __shared__ float gg[8][256];      // 8 KB
    __shared__ float ga[8][256];      // 8 KB
    __shared__ float ln2[8][256];     // 8 KB
    __shared__ float fh1[8][128];     // 4 KB
    __shared__ float partS[8][24];
    __shared__ float fhsh[8][6];
    __shared__ float red2[2][4][4][2];

    const int i0 = blockIdx.x * 8;
    const int tid = threadIdx.x;

    ash[tid >> 6][tid & 63] = asumG[(size_t)i0 * HH + tid];
    __syncthreads();

    // gates: thread = (gate = tid>>8, c = tid&255); K=64
    {
        const int c = tid & 255;
        const int gate = tid >> 8;
        const float* wp = WfusS + gate * 256 + c;
        float acc[8];
#pragma unroll
        for (int t = 0; t < 8; t++) acc[t] = 0.0f;
#pragma unroll 4
        for (int k = 0; k < HH; k++) {
            float w = wp[(size_t)k * 512];
#pragma unroll
            for (int t = 0; t < 8; t++) acc[t] = fmaf(ash[t][k], w, acc[t]);
        }
        float* dst = gate ? &ga[0][0] : &gg[0][0];
#pragma unroll
        for (int t = 0; t < 8; t++)
            dst[t * 256 + c] = acc[t] + gpreHS[(size_t)(i0 + t) * 512 + gate * 256 + c];
    }
    __syncthreads();

    // h_aug + LN2: thread = (tp = tid>>8, d = tid&255), tokens t = tp*4+tt
    const int d = tid & 255;
    const int tp = tid >> 8;
    const int wv = tid >> 6;          // 0..7
    const int wvg = wv & 3;
    const int lane = tid & 63;
    float haug[4];
#pragma unroll
    for (int tt = 0; tt < 4; tt++) {
        int t = tp * 4 + tt;
        float hv = hIn[(size_t)(i0 + t) * DD + d];
        haug[tt] = hv + sigmoidf_(ga[t][d]) * gg[t][d];
    }
    {
        float s1[4], s2[4];
#pragma unroll
        for (int tt = 0; tt < 4; tt++) { s1[tt] = haug[tt]; s2[tt] = haug[tt] * haug[tt]; }
#pragma unroll
        for (int off = 32; off > 0; off >>= 1) {
#pragma unroll
            for (int tt = 0; tt < 4; tt++) {
                s1[tt] += __shfl_xor(s1[tt], off);
                s2[tt] += __shfl_xor(s2[tt], off);
            }
        }
        if (lane == 0) {
#pragma unroll
            for (int tt = 0; tt < 4; tt++) {
                red2[tp][tt][wvg][0] = s1[tt];
                red2[tp][tt][wvg][1] = s2[tt];
            }
        }
    }
    __syncthreads();
    {
        float gv = fhlng[d], bv = fhlnb[d];
#pragma unroll
        for (int tt = 0; tt < 4; tt++) {
            float S1 = red2[tp][tt][0][0] + red2[tp][tt][1][0] + red2[tp][tt][2][0] + red2[tp][tt][3][0];
            float S2 = red2[tp][tt][0][1] + red2[tp][tt][1][1] + red2[tp][tt][2][1] + red2[tp][tt][3][1];
            float mu = S1 * (1.0f / DD);
            float var = S2 * (1.0f / DD) - mu * mu;
            float rs = rsqrtf(var + 1e-5f);
            ln2[tp * 4 + tt][d] = (haug[tt] - mu) * rs * gv + bv;
        }
    }
    __syncthreads();

    // fh1: tok = tid>>6 (0..7), 2 cols per thread, K=256
    {
        const int tok = tid >> 6;
        const int c2 = (tid & 63) * 2;
        float a0 = fhb1[c2], a1 = fhb1[c2 + 1];
        const float* lp = &ln2[tok][0];
#pragma unroll 4
        for (int k = 0; k < DD; k++) {
            float lv = lp[k];
            float2 w2v = *(const float2*)&fhw1[(size_t)k * 128 + c2];
            a0 = fmaf(lv, w2v.x, a0);
            a1 = fmaf(lv, w2v.y, a1);
        }
        fh1[tok][c2] = geluf(a0);
        fh1[tok][c2 + 1] = geluf(a1);
    }
    __syncthreads();

    // fh2: 8 tok x 6 m x 4 kq = 192 threads
    if (tid < 192) {
        const int t = tid / 24, rem = tid % 24;
        const int m = rem >> 2, kq = rem & 3;
        float a = 0.0f;
#pragma unroll
        for (int j = 0; j < 32; j++) {
            int k = kq * 32 + j;
            a = fmaf(fh1[t][k], fhw2[k * 6 + m], a);
        }
        partS[t][m * 4 + kq] = a;
    }
    __syncthreads();
    if (tid < 48) {
        const int t = tid / 6, m = tid % 6;
        fhsh[t][m] = partS[t][m * 4 + 0] + partS[t][m * 4 + 1]
                   + partS[t][m * 4 + 2] + partS[t][m * 4 + 3] + fhb2[m];
    }
    __syncthreads();

    // frame update + atoms: one thread per token
    if (tid < 8) {
        const int t = tid;
        const int i = i0 + t;
        float R9[9], t3[3];
#pragma unroll
        for (int k = 0; k < 9; k++) R9[k] = Rin[(size_t)i * 9 + k];
#pragma unroll
        for (int k = 0; k < 3; k++) t3[k] = tin[(size_t)i * 3 + k];
        float drx = fhsh[t][0], dry = fhsh[t][1], drz = fhsh[t][2];
        float dtx = fhsh[t][3], dty = fhsh[t][4], dtz = fhsh[t][5];
        float ang = fmaxf(sqrtf(drx * drx + dry * dry + drz * drz), 1e-8f);
        float ax = drx / ang, ay = dry / ang, az = drz / ang;
        float ca = cosf(ang), sa = sinf(ang), omc = 1.0f - ca;
        float Rd[9];
        Rd[0] = ca + omc * ax * ax;        Rd[1] = -sa * az + omc * ax * ay;  Rd[2] = sa * ay + omc * ax * az;
        Rd[3] = sa * az + omc * ay * ax;   Rd[4] = ca + omc * ay * ay;        Rd[5] = -sa * ax + omc * ay * az;
        Rd[6] = -sa * ay + omc * az * ax;  Rd[7] = sa * ax + omc * az * ay;   Rd[8] = ca + omc * az * az;
        float Rn[9];
#pragma unroll
        for (int x = 0; x < 3; x++)
#pragma unroll
            for (int y = 0; y < 3; y++)
                Rn[x * 3 + y] = Rd[x * 3 + 0] * R9[0 * 3 + y]
                              + Rd[x * 3 + 1] * R9[1 * 3 + y]
                              + Rd[x * 3 + 2] * R9[2 * 3 + y];
        float tn[3];
#pragma unroll
        for (int x = 0; x < 3; x++)
            tn[x] = t3[x] + R9[x * 3 + 0] * dtx + R9[x * 3 + 1] * dty + R9[x * 3 + 2] * dtz;
#pragma unroll
        for (int k = 0; k < 9; k++) Rout[(size_t)i * 9 + k] = Rn[k];
#pragma unroll
        for (int k = 0; k < 3; k++) tout[(size_t)i * 3 + k] = tn[k];
        float* os = outStack + ((size_t)s * NTOK + i) * 9;
        float av[9];
#pragma unroll
        for (int x = 0; x < 3; x++) {
            float r0 = Rn[x * 3 + 0], r1 = Rn[x * 3 + 1];
            av[0 * 3 + x] = tn[x] - 0.9f * r0 + 1.2f * r1;
            av[1 * 3 + x] = tn[x];
            av[2 * 3 + x] = tn[x] + 2.5f * r0;
        }
#pragma unroll
        for (int k = 0; k < 9; k++) os[k] = av[k];
        if (s == NSTEP - 1) {
            float* of = outFinal + (size_t)i * 9;
#pragma unroll
            for (int k = 0; k < 9; k++) of[k] = av[k];
        }
    }
}

// ---------------------------------------------------------------------------
extern "C" void kernel_launch(void* const* d_in, const int* in_sizes, int n_in,
                              void* d_out, int out_size, void* d_ws, size_t ws_size,
                              hipStream_t stream) {
    const float* h      = (const float*)d_in[0];
    const float* coords = (const float*)d_in[1];
    const float* pw1   = (const float*)d_in[3];
    const float* pb1   = (const float*)d_in[4];
    const float* pw2   = (const float*)d_in[5];
    const float* pb2   = (const float*)d_in[6];
    const float* gww   = (const float*)d_in[7];
    const float* gwb   = (const float*)d_in[8];
    const float* gaw   = (const float*)d_in[9];
    const float* gab   = (const float*)d_in[10];
    const float* lng   = (const float*)d_in[11];
    const float* lnb   = (const float*)d_in[12];
    const float* fhlng = (const float*)d_in[13];
    const float* fhlnb = (const float*)d_in[14];
    const float* fhw1  = (const float*)d_in[15];
    const float* fhb1  = (const float*)d_in[16];
    const float* fhw2  = (const float*)d_in[17];
    const float* fhb2  = (const float*)d_in[18];

    float* ws     = (float*)d_ws;
    float* R0     = ws;                         // 9216
    float* t0     = ws + 9216;                  // 3072
    float* R1     = ws + 12288;                 // 9216
    float* t1     = ws + 21504;                 // 3072
    float* hln    = ws + 24576;                 // 1048576
    float* gpreH  = ws + 24576 + 1048576;       // 2097152
    float* Wfus   = ws + 24576 + 1048576 + 2097152;          // 131072
    float* biasGA = ws + 24576 + 1048576 + 2097152 + 131072; // 2048
    float* w1f    = ws + 24576 + 1048576 + 2097152 + 131072 + 2048; // 2048
    float* asumG  = ws + 24576 + 1048576 + 2097152 + 131072 + 2048 + 2048; // 65536

    float* outFinal = (float*)d_out;
    float* outStack = outFinal + NTOK * 9;

    build_frames_kernel<<<NTOK / 256, 256, 0, stream>>>(coords, R0, t0);
    ln4_kernel<<<NTOK, 256, 0, stream>>>(h, lng, lnb, hln);
    fold_w1_kernel<<<NSTEP, 64, 0, stream>>>(pw1, pb1, w1f);
    fuse_w_kernel<<<128, 256, 0, stream>>>(pw2, pb2, gww, gaw, gwb, gab, Wfus, biasGA);
    gpreh_kernel<<<512, 256, 0, stream>>>(hln, gww, gaw, biasGA, gpreH);

    for (int s = 0; s < NSTEP; s++) {
        const float* Rin = (s & 1) ? R1 : R0;
        const float* tin = (s & 1) ? t1 : t0;
        float* Rout = (s & 1) ? R0 : R1;
        float* tout = (s & 1) ? t0 : t1;
        pair_kernel<<<NTOK, 256, 0, stream>>>(
            Rin, tin, w1f + (size_t)s * HH * 8, asumG);
        epi_kernel<<<NTOK / 8, 512, 0, stream>>>(
            Rin, tin, Rout, tout, asumG,
            Wfus + (size_t)s * HH * 512, gpreH + (size_t)s * NTOK * 512,
            h, fhlng, fhlnb, fhw1, fhb1, fhw2, fhb2,
            outFinal, outStack, s);
    }
}

// Round 11
// 212.575 us; speedup vs baseline: 1.3184x; 1.3184x over previous
//
#include <hip/hip_runtime.h>
#include <math.h>

// Problem constants (from setup_inputs: B=2, L=512, D=256, H=64, S=4)
#define BB 2
#define LL 512
#define DD 256
#define HH 64
#define NSTEP 4
#define NTOK (BB * LL)   // 1024

__device__ __forceinline__ float geluf(float x) {
    return 0.5f * x * (1.0f + erff(x * 0.70710678118654752f));
}
__device__ __forceinline__ float sigmoidf_(float x) {
    return 1.0f / (1.0f + expf(-x));
}
#define F4C(v, j) ((j) == 0 ? (v).x : (j) == 1 ? (v).y : (j) == 2 ? (v).z : (v).w)

// ---------------------------------------------------------------------------
// Kernel 0: build frames from coords.
// ---------------------------------------------------------------------------
__global__ void build_frames_kernel(const float* __restrict__ coords,
                                    float* __restrict__ Rg, float* __restrict__ tg) {
    int idx = blockIdx.x * blockDim.x + threadIdx.x;
    if (idx >= NTOK) return;
    const float* c = coords + idx * 9;
    float Px = c[0], Py = c[1], Pz = c[2];
    float Cx = c[3], Cy = c[4], Cz = c[5];
    float Nx = c[6], Ny = c[7], Nz = c[8];
    float e1x = Nx - Cx, e1y = Ny - Cy, e1z = Nz - Cz;
    float n1 = fmaxf(sqrtf(e1x * e1x + e1y * e1y + e1z * e1z), 1e-12f);
    e1x /= n1; e1y /= n1; e1z /= n1;
    float ux = Px - Cx, uy = Py - Cy, uz = Pz - Cz;
    float du = ux * e1x + uy * e1y + uz * e1z;
    float e2x = ux - du * e1x, e2y = uy - du * e1y, e2z = uz - du * e1z;
    float n2 = fmaxf(sqrtf(e2x * e2x + e2y * e2y + e2z * e2z), 1e-12f);
    e2x /= n2; e2y /= n2; e2z /= n2;
    float e3x = e1y * e2z - e1z * e2y;
    float e3y = e1z * e2x - e1x * e2z;
    float e3z = e1x * e2y - e1y * e2x;
    float* Rp = Rg + idx * 9;
    Rp[0] = e1x; Rp[1] = e2x; Rp[2] = e3x;
    Rp[3] = e1y; Rp[4] = e2y; Rp[5] = e3y;
    Rp[6] = e1z; Rp[7] = e2z; Rp[8] = e3z;
    tg[idx * 3 + 0] = Cx; tg[idx * 3 + 1] = Cy; tg[idx * 3 + 2] = Cz;
}

// ---------------------------------------------------------------------------
// Kernel A (once): all 4 steps' LayerNorm of h -> hln[s][i][k]
// ---------------------------------------------------------------------------
__global__ __launch_bounds__(256) void ln4_kernel(
        const float* __restrict__ hIn,
        const float* __restrict__ lng, const float* __restrict__ lnb,
        float* __restrict__ hln) {
    __shared__ float redsh[8];
    const int i = blockIdx.x;
    const int tid = threadIdx.x;
    const int wv = tid >> 6, lane = tid & 63;
    float hv = hIn[(size_t)i * DD + tid];
    float s1 = hv, s2 = hv * hv;
#pragma unroll
    for (int off = 32; off > 0; off >>= 1) {
        s1 += __shfl_xor(s1, off);
        s2 += __shfl_xor(s2, off);
    }
    if (lane == 0) { redsh[wv * 2] = s1; redsh[wv * 2 + 1] = s2; }
    __syncthreads();
    float S1 = redsh[0] + redsh[2] + redsh[4] + redsh[6];
    float S2 = redsh[1] + redsh[3] + redsh[5] + redsh[7];
    float mu = S1 * (1.0f / DD);
    float var = S2 * (1.0f / DD) - mu * mu;
    float rs = rsqrtf(var + 1e-5f);
    float hn = (hv - mu) * rs;
#pragma unroll
    for (int s = 0; s < NSTEP; s++)
        hln[((size_t)s * NTOK + i) * DD + tid] = hn * lng[s * DD + tid] + lnb[s * DD + tid];
}

// ---------------------------------------------------------------------------
// Kernel B (once): Wfus[s][64][512] = (w2[s] @ Wbot)/512, biasGA.
// ---------------------------------------------------------------------------
__global__ __launch_bounds__(256) void fuse_w_kernel(
        const float* __restrict__ w2all, const float* __restrict__ b2all,
        const float* __restrict__ gww, const float* __restrict__ gaw,
        const float* __restrict__ gwb, const float* __restrict__ gab,
        float* __restrict__ Wfus, float* __restrict__ biasGA) {
    __shared__ float bsh[256 * 17];   // 17 KB, padded stride 17

    const int bid = blockIdx.x;
    const int s = bid >> 5;
    const int gate = (bid >> 4) & 1;
    const int ct = bid & 15;
    const int c0 = ct * 16;
    const int tid = threadIdx.x;

    const float* Wb = (gate ? gaw : gww) + (size_t)s * 2 * DD * DD + (size_t)DD * DD;
    {
        const float* src = Wb + (size_t)tid * DD + c0;
        float4 a0 = *(const float4*)(src + 0);
        float4 a1 = *(const float4*)(src + 4);
        float4 a2 = *(const float4*)(src + 8);
        float4 a3 = *(const float4*)(src + 12);
        float* dst = &bsh[tid * 17];
        dst[0] = a0.x; dst[1] = a0.y; dst[2] = a0.z; dst[3] = a0.w;
        dst[4] = a1.x; dst[5] = a1.y; dst[6] = a1.z; dst[7] = a1.w;
        dst[8] = a2.x; dst[9] = a2.y; dst[10] = a2.z; dst[11] = a2.w;
        dst[12] = a3.x; dst[13] = a3.y; dst[14] = a3.z; dst[15] = a3.w;
    }
    __syncthreads();

    const int r = tid & 63;
    const int cg = tid >> 6;
    const float* w2p = w2all + (size_t)s * HH * DD + (size_t)r * DD;
    float4 acc = {0.f, 0.f, 0.f, 0.f};
#pragma unroll 4
    for (int k4 = 0; k4 < 64; k4++) {
        float4 wv = *(const float4*)(w2p + k4 * 4);
#pragma unroll
        for (int j = 0; j < 4; j++) {
            const float* bp = &bsh[(k4 * 4 + j) * 17 + cg * 4];
            float w = F4C(wv, j);
            acc.x = fmaf(w, bp[0], acc.x);
            acc.y = fmaf(w, bp[1], acc.y);
            acc.z = fmaf(w, bp[2], acc.z);
            acc.w = fmaf(w, bp[3], acc.w);
        }
    }
    acc.x *= (1.0f / 512.0f); acc.y *= (1.0f / 512.0f);
    acc.z *= (1.0f / 512.0f); acc.w *= (1.0f / 512.0f);
    *(float4*)&Wfus[((size_t)s * HH + r) * 512 + gate * 256 + c0 + cg * 4] = acc;

    if (tid < 16) {
        const float* b2 = b2all + s * DD;
        float a = 0.0f;
#pragma unroll 4
        for (int m = 0; m < 256; m++) a = fmaf(b2[m], bsh[m * 17 + tid], a);
        const float* gb = (gate ? gab : gwb) + s * DD;
        biasGA[(size_t)s * 512 + gate * 256 + c0 + tid] = a + gb[c0 + tid];
    }
}

// ---------------------------------------------------------------------------
// Kernel C (once): gpreH[s][i][gate*256+col] = hln[s][i] @ Wtop + biasGA.
// ---------------------------------------------------------------------------
__global__ __launch_bounds__(256) void gpreh_kernel(
        const float* __restrict__ hln,
        const float* __restrict__ gww, const float* __restrict__ gaw,
        const float* __restrict__ biasGA,
        float* __restrict__ gpreH) {
    __shared__ float hsh[16 * DD];   // 16 KB
    const int bid = blockIdx.x;
    const int s = bid >> 7;
    const int gate = (bid >> 6) & 1;
    const int mt = bid & 63;
    const int tid = threadIdx.x;     // = col

    const float* hsrc = hln + ((size_t)s * NTOK + mt * 16) * DD;
    for (int k = tid; k < 16 * DD; k += 256) hsh[k] = hsrc[k];
    __syncthreads();

    const float* W = (gate ? gaw : gww) + (size_t)s * 2 * DD * DD;  // top half
    float bias = biasGA[(size_t)s * 512 + gate * 256 + tid];
    float acc[16];
#pragma unroll
    for (int t = 0; t < 16; t++) acc[t] = bias;
#pragma unroll 4
    for (int k = 0; k < DD; k++) {
        float w = W[(size_t)k * DD + tid];
#pragma unroll
        for (int t = 0; t < 16; t++) acc[t] = fmaf(hsh[t * DD + k], w, acc[t]);
    }
    float* out = gpreH + ((size_t)s * NTOK + mt * 16) * 512 + gate * 256 + tid;
#pragma unroll
    for (int t = 0; t < 16; t++) out[(size_t)t * 512] = acc[t];
}

// ---------------------------------------------------------------------------
// Kernel D1 (per step): PAIR — exact round-1 structure (measured ~4 us/step).
// AoS feats[256][9] in LDS; phase B: wave g consumes rows [g*64,g*64+64),
// lane = h, broadcast LDS reads; libm geluf; accbuf reduce -> asumG.
// ---------------------------------------------------------------------------
__global__ __launch_bounds__(256) void pair_kernel(
        const float* __restrict__ Rin, const float* __restrict__ tin,
        const float* __restrict__ w1, const float* __restrict__ b1,
        float* __restrict__ asumG) {
    __shared__ float Rsh[LL * 9];     // 18 KB
    __shared__ float tsh[LL * 3];     // 6 KB
    __shared__ float w1sh[7 * HH];
    __shared__ float b1sh[HH];
    __shared__ float feats[256][9];   // 9 KB
    __shared__ float accbuf[4 * HH];

    const int i = blockIdx.x;
    const int b = i >> 9;
    const int l = i & (LL - 1);
    const int tid = threadIdx.x;

    const float* Rb = Rin + (size_t)b * LL * 9;
    const float* tb = tin + (size_t)b * LL * 3;
    for (int k = tid; k < LL * 9; k += 256) Rsh[k] = Rb[k];
    for (int k = tid; k < LL * 3; k += 256) tsh[k] = tb[k];
    for (int k = tid; k < 7 * HH; k += 256) w1sh[k] = w1[k];
    if (tid < HH) b1sh[tid] = b1[tid];
    __syncthreads();

    float Ri[9];
#pragma unroll
    for (int k = 0; k < 9; k++) Ri[k] = Rsh[l * 9 + k];
    const float tix = tsh[l * 3 + 0], tiy = tsh[l * 3 + 1], tiz = tsh[l * 3 + 2];

    const int g = tid >> 6;
    const int hh = tid & 63;
    // hoist per-lane weights into registers
    const float wv0 = w1sh[0 * HH + hh];
    const float wv1 = w1sh[1 * HH + hh];
    const float wv2 = w1sh[2 * HH + hh];
    const float wv3 = w1sh[3 * HH + hh];
    const float wv4 = w1sh[4 * HH + hh];
    const float wv5 = w1sh[5 * HH + hh];
    const float wv6 = w1sh[6 * HH + hh];
    const float bb  = b1sh[hh];
    float acc = 0.0f;

    for (int jc = 0; jc < LL; jc += 256) {
        {
            const int j = jc + tid;
            float dx = tsh[j * 3 + 0] - tix;
            float dy = tsh[j * 3 + 1] - tiy;
            float dz = tsh[j * 3 + 2] - tiz;
            float dl0 = Ri[0] * dx + Ri[3] * dy + Ri[6] * dz;
            float dl1 = Ri[1] * dx + Ri[4] * dy + Ri[7] * dz;
            float dl2 = Ri[2] * dx + Ri[5] * dy + Ri[8] * dz;
            float d2 = dx * dx + dy * dy + dz * dz;
            float dist = fmaxf(sqrtf(d2), 1e-4f);
            float tr = 0.0f;
#pragma unroll
            for (int k = 0; k < 9; k++) tr += Ri[k] * Rsh[j * 9 + k];
            float ca = fminf(fmaxf((tr - 1.0f) * 0.5f, -1.0f), 1.0f);
            feats[tid][0] = dist;
            feats[tid][1] = dl0;
            feats[tid][2] = dl1;
            feats[tid][3] = dl2;
            feats[tid][4] = tr;
            feats[tid][5] = ca;
            feats[tid][6] = logf(dist);
        }
        __syncthreads();
#pragma unroll 4
        for (int jj = 0; jj < 64; jj++) {
            const int fl = g * 64 + jj;           // broadcast LDS reads
            float x = bb;
            x = fmaf(feats[fl][0], wv0, x);
            x = fmaf(feats[fl][1], wv1, x);
            x = fmaf(feats[fl][2], wv2, x);
            x = fmaf(feats[fl][3], wv3, x);
            x = fmaf(feats[fl][4], wv4, x);
            x = fmaf(feats[fl][5], wv5, x);
            x = fmaf(feats[fl][6], wv6, x);
            acc += geluf(x);
        }
        __syncthreads();
    }
    accbuf[g * HH + hh] = acc;
    __syncthreads();
    if (tid < HH)
        asumG[(size_t)i * HH + tid] = accbuf[tid] + accbuf[HH + tid]
                                    + accbuf[2 * HH + tid] + accbuf[3 * HH + tid];
}

// ---------------------------------------------------------------------------
// Kernel D2 (per step): EPILOGUE — 4 tokens/block, 1024 threads, grid 256
// (16 waves/CU = 4/SIMD). Flat phases: thread=(t,d) computes both gates,
// h_aug in-register, wave-shfl LN, fh1 split-K x2, fh2, frame update.
// ---------------------------------------------------------------------------
__global__ __launch_bounds__(1024) void epi_kernel(
        const float* __restrict__ Rin, const float* __restrict__ tin,
        float* __restrict__ Rout, float* __restrict__ tout,
        const float* __restrict__ asumG,
        const float* __restrict__ WfusS, const float* __restrict__ gpreHS,
        const float* __restrict__ hIn,
        const float* __restrict__ fhlng, const float* __restrict__ fhlnb,
        const float* __restrict__ fhw1, const float* __restrict__ fhb1,
        const float* __restrict__ fhw2, const float* __restrict__ fhb2,
        float* __restrict__ outFinal, float* __restrict__ outStack, int s) {
    __shared__ float ash[4][HH];       // 1 KB
    __shared__ float ln2[4][DD];       // 4 KB
    __shared__ float fh1p[4][2][128];  // 4 KB
    __shared__ float fh1[4][128];      // 2 KB
    __shared__ float partS[4][24];
    __shared__ float fhsh[4][6];
    __shared__ float red2[4][4][2];

    const int i0 = blockIdx.x * 4;
    const int tid = threadIdx.x;
    const int t = tid >> 8;           // token 0..3
    const int d = tid & 255;          // col 0..255
    const int lane = tid & 63;

    if (tid < 4 * HH) ash[tid >> 6][tid & 63] = asumG[(size_t)i0 * HH + tid];
    __syncthreads();

    // ---- both gates, K=64 (Wfus L2-resident; 2 independent chains)
    float ag = 0.0f, aa = 0.0f;
    {
        const float* wg = WfusS + d;
        const float* wa = WfusS + 256 + d;
        const float* av = &ash[t][0];
#pragma unroll 8
        for (int k = 0; k < HH; k++) {
            float a = av[k];
            ag = fmaf(a, wg[(size_t)k * 512], ag);
            aa = fmaf(a, wa[(size_t)k * 512], aa);
        }
    }
    ag += gpreHS[(size_t)(i0 + t) * 512 + d];
    aa += gpreHS[(size_t)(i0 + t) * 512 + 256 + d];
    float hv = hIn[(size_t)(i0 + t) * DD + d];
    float haug = hv + sigmoidf_(aa) * ag;

    // ---- LN2 (wave covers 64 d's of one token; 4 waves/token)
    {
        float s1 = haug, s2 = haug * haug;
#pragma unroll
        for (int off = 32; off > 0; off >>= 1) {
            s1 += __shfl_xor(s1, off);
            s2 += __shfl_xor(s2, off);
        }
        if (lane == 0) {
            red2[t][(tid >> 6) & 3][0] = s1;
            red2[t][(tid >> 6) & 3][1] = s2;
        }
    }
    __syncthreads();
    {
        float S1 = red2[t][0][0] + red2[t][1][0] + red2[t][2][0] + red2[t][3][0];
        float S2 = red2[t][0][1] + red2[t][1][1] + red2[t][2][1] + red2[t][3][1];
        float mu = S1 * (1.0f / DD);
        float var = S2 * (1.0f / DD) - mu * mu;
        float rs = rsqrtf(var + 1e-5f);
        ln2[t][d] = (haug - mu) * rs * fhlng[d] + fhlnb[d];
    }
    __syncthreads();

    // ---- fh1: thread = (t, kh=(tid>>7)&1, col=tid&127); K=128 partial
    {
        const int col = tid & 127;
        const int kh = (tid >> 7) & 1;
        const float* lp = &ln2[t][kh * 128];
        const float* wp = fhw1 + (size_t)(kh * 128) * 128 + col;
        float a = 0.0f;
#pragma unroll 8
        for (int k = 0; k < 128; k++) a = fmaf(lp[k], wp[(size_t)k * 128], a);
        fh1p[t][kh][col] = a;
    }
    __syncthreads();
    if (tid < 512) {
        const int t2 = tid >> 7, col = tid & 127;
        fh1[t2][col] = geluf(fh1p[t2][0][col] + fh1p[t2][1][col] + fhb1[col]);
    }
    __syncthreads();

    // ---- fh2: 4 tok x 6 outs x 4 K-quarters
    if (tid < 96) {
        const int tt = tid / 24, rem = tid % 24;
        const int m = rem >> 2, kq = rem & 3;
        float a = 0.0f;
#pragma unroll
        for (int j = 0; j < 32; j++) {
            int k = kq * 32 + j;
            a = fmaf(fh1[tt][k], fhw2[k * 6 + m], a);
        }
        partS[tt][m * 4 + kq] = a;
    }
    __syncthreads();
    if (tid < 24) {
        const int tt = tid / 6, m = tid % 6;
        fhsh[tt][m] = partS[tt][m * 4 + 0] + partS[tt][m * 4 + 1]
                    + partS[tt][m * 4 + 2] + partS[tt][m * 4 + 3] + fhb2[m];
    }
    __syncthreads();

    // ---- frame update + atoms: one thread per token
    if (tid < 4) {
        const int tt = tid;
        const int i = i0 + tt;
        float R9[9], t3[3];
#pragma unroll
        for (int k = 0; k < 9; k++) R9[k] = Rin[(size_t)i * 9 + k];
#pragma unroll
        for (int k = 0; k < 3; k++) t3[k] = tin[(size_t)i * 3 + k];
        float drx = fhsh[tt][0], dry = fhsh[tt][1], drz = fhsh[tt][2];
        float dtx = fhsh[tt][3], dty = fhsh[tt][4], dtz = fhsh[tt][5];
        float ang = fmaxf(sqrtf(drx * drx + dry * dry + drz * drz), 1e-8f);
        float ax = drx / ang, ay = dry / ang, az = drz / ang;
        float ca = cosf(ang), sa = sinf(ang), omc = 1.0f - ca;
        float Rd[9];
        Rd[0] = ca + omc * ax * ax;        Rd[1] = -sa * az + omc * ax * ay;  Rd[2] = sa * ay + omc * ax * az;
        Rd[3] = sa * az + omc * ay * ax;   Rd[4] = ca + omc * ay * ay;        Rd[5] = -sa * ax + omc * ay * az;
        Rd[6] = -sa * ay + omc * az * ax;  Rd[7] = sa * ax + omc * az * ay;   Rd[8] = ca + omc * az * az;
        float Rn[9];
#pragma unroll
        for (int x = 0; x < 3; x++)
#pragma unroll
            for (int y = 0; y < 3; y++)
                Rn[x * 3 + y] = Rd[x * 3 + 0] * R9[0 * 3 + y]
                              + Rd[x * 3 + 1] * R9[1 * 3 + y]
                              + Rd[x * 3 + 2] * R9[2 * 3 + y];
        float tn[3];
#pragma unroll
        for (int x = 0; x < 3; x++)
            tn[x] = t3[x] + R9[x * 3 + 0] * dtx + R9[x * 3 + 1] * dty + R9[x * 3 + 2] * dtz;
#pragma unroll
        for (int k = 0; k < 9; k++) Rout[(size_t)i * 9 + k] = Rn[k];
#pragma unroll
        for (int k = 0; k < 3; k++) tout[(size_t)i * 3 + k] = tn[k];
        float* os = outStack + ((size_t)s * NTOK + i) * 9;
        float av[9];
#pragma unroll
        for (int x = 0; x < 3; x++) {
            float r0 = Rn[x * 3 + 0], r1 = Rn[x * 3 + 1];
            av[0 * 3 + x] = tn[x] - 0.9f * r0 + 1.2f * r1;
            av[1 * 3 + x] = tn[x];
            av[2 * 3 + x] = tn[x] + 2.5f * r0;
        }
#pragma unroll
        for (int k = 0; k < 9; k++) os[k] = av[k];
        if (s == NSTEP - 1) {
            float* of = outFinal + (size_t)i * 9;
#pragma unroll
            for (int k = 0; k < 9; k++) of[k] = av[k];
        }
    }
}

// ---------------------------------------------------------------------------
extern "C" void kernel_launch(void* const* d_in, const int* in_sizes, int n_in,
                              void* d_out, int out_size, void* d_ws, size_t ws_size,
                              hipStream_t stream) {
    const float* h      = (const float*)d_in[0];
    const float* coords = (const float*)d_in[1];
    const float* pw1   = (const float*)d_in[3];
    const float* pb1   = (const float*)d_in[4];
    const float* pw2   = (const float*)d_in[5];
    const float* pb2   = (const float*)d_in[6];
    const float* gww   = (const float*)d_in[7];
    const float* gwb   = (const float*)d_in[8];
    const float* gaw   = (const float*)d_in[9];
    const float* gab   = (const float*)d_in[10];
    const float* lng   = (const float*)d_in[11];
    const float* lnb   = (const float*)d_in[12];
    const float* fhlng = (const float*)d_in[13];
    const float* fhlnb = (const float*)d_in[14];
    const float* fhw1  = (const float*)d_in[15];
    const float* fhb1  = (const float*)d_in[16];
    const float* fhw2  = (const float*)d_in[17];
    const float* fhb2  = (const float*)d_in[18];

    float* ws     = (float*)d_ws;
    float* R0     = ws;                         // 9216
    float* t0     = ws + 9216;                  // 3072
    float* R1     = ws + 12288;                 // 9216
    float* t1     = ws + 21504;                 // 3072
    float* hln    = ws + 24576;                 // 1048576
    float* gpreH  = ws + 24576 + 1048576;       // 2097152
    float* Wfus   = ws + 24576 + 1048576 + 2097152;          // 131072
    float* biasGA = ws + 24576 + 1048576 + 2097152 + 131072; // 2048
    float* asumG  = ws + 24576 + 1048576 + 2097152 + 131072 + 2048; // 65536

    float* outFinal = (float*)d_out;
    float* outStack = outFinal + NTOK * 9;

    build_frames_kernel<<<NTOK / 256, 256, 0, stream>>>(coords, R0, t0);
    ln4_kernel<<<NTOK, 256, 0, stream>>>(h, lng, lnb, hln);
    fuse_w_kernel<<<128, 256, 0, stream>>>(pw2, pb2, gww, gaw, gwb, gab, Wfus, biasGA);
    gpreh_kernel<<<512, 256, 0, stream>>>(hln, gww, gaw, biasGA, gpreH);

    for (int s = 0; s < NSTEP; s++) {
        const float* Rin = (s & 1) ? R1 : R0;
        const float* tin = (s & 1) ? t1 : t0;
        float* Rout = (s & 1) ? R0 : R1;
        float* tout = (s & 1) ? t0 : t1;
        pair_kernel<<<NTOK, 256, 0, stream>>>(
            Rin, tin, pw1 + s * 7 * HH, pb1 + s * HH, asumG);
        epi_kernel<<<NTOK / 4, 1024, 0, stream>>>(
            Rin, tin, Rout, tout, asumG,
            Wfus + (size_t)s * HH * 512, gpreH + (size_t)s * NTOK * 512,
            h, fhlng, fhlnb, fhw1, fhb1, fhw2, fhb2,
            outFinal, outStack, s);
    }
}